// Round 14
// baseline (167.582 us; speedup 1.0000x reference)
//
#include <hip/hip_runtime.h>
#include <hip/hip_bf16.h>
#include <math.h>

#define B_ 16
#define C_ 64
#define POS_BIG (1e30f)
#define L2E 1.44269504088896340736f
#define LN2 0.69314718055994530942f

typedef __attribute__((ext_vector_type(8))) short bf16x8;
typedef __attribute__((ext_vector_type(4))) float f32x4;

__device__ __forceinline__ short f2bf(float x) {
  __hip_bfloat16 h = __float2bfloat16(x);
  return *reinterpret_cast<short*>(&h);
}

// ---- compile-time tables (fixed problem B=16, T=1024, C=64) ----
// temporal: 576 blocks (128 rows each, 8 waves x 16 rows); starts per level l=0..9
__device__ constexpr int kTS[10]   = {0, 256, 384, 448, 480, 496, 512, 528, 544, 560};
__device__ constexpr int kZOff[10] = {0, 2097152, 3145728, 3670016, 3932160, 4063232,
                                      4128768, 4161536, 4177920, 4186112};               // shorts
// instance: 513 blocks; starts per level l=0..10
__device__ constexpr int kIS[11] = {0, 256, 384, 448, 480, 496, 504, 508, 510, 511, 512};
// f32 pyramid offsets in ws (floats), l=1..10
__device__ constexpr int kO1[11] = {0, 0, 1056768, 1585152, 1849344, 1981440, 2047488,
                                    2080512, 2097024, 2105280, 2109408};
__device__ constexpr int kO2[11] = {0, 524288, 1318912, 1716224, 1914880, 2014208, 2063872,
                                    2088704, 2101120, 2107328, 2110432};
__device__ constexpr int kOT[11] = {0, 1048576, 1581056, 1847296, 1980416, 2046976, 2080256,
                                    2096896, 2105216, 2109376, 2111456};

#define NTEMP 576
#define NINST 513

// ---------------- pyramid stage 1: L0 bf16 convert + levels 1..5 direct from L0 ----------------
__global__ __launch_bounds__(256) void pyramid1_kernel(
    const float* __restrict__ z1, const float* __restrict__ z2, const float* __restrict__ t,
    float* __restrict__ ws, short* __restrict__ zcb)
{
  int idx = blockIdx.x * 256 + threadIdx.x;
  if (idx < 131072) {
    int n = idx * 8;
    int b = n >> 16;
    float4 u1 = *(const float4*)(z1 + n), v1 = *(const float4*)(z1 + n + 4);
    float4 u2 = *(const float4*)(z2 + n), v2 = *(const float4*)(z2 + n + 4);
    bf16x8 f1, f2;
    f1[0]=f2bf(u1.x); f1[1]=f2bf(u1.y); f1[2]=f2bf(u1.z); f1[3]=f2bf(u1.w);
    f1[4]=f2bf(v1.x); f1[5]=f2bf(v1.y); f1[6]=f2bf(v1.z); f1[7]=f2bf(v1.w);
    f2[0]=f2bf(u2.x); f2[1]=f2bf(u2.y); f2[2]=f2bf(u2.z); f2[3]=f2bf(u2.w);
    f2[4]=f2bf(v2.x); f2[5]=f2bf(v2.y); f2[6]=f2bf(v2.z); f2[7]=f2bf(v2.w);
    *(bf16x8*)(zcb + (size_t)n + (size_t)b * 65536) = f1;
    *(bf16x8*)(zcb + (size_t)n + (size_t)(b + 1) * 65536) = f2;
  } else if (idx < 1146880) {
    int li = idx - 131072;
    int l = 1, st = 0;
    if (li >= 524288) { l = 2; st = 524288; }
    if (li >= 786432) { l = 3; st = 786432; }
    if (li >= 917504) { l = 4; st = 917504; }
    if (li >= 983040) { l = 5; st = 983040; }
    int k = li - st;
    int c = k & 63, bi = k >> 6;
    int Tl = 1024 >> l;
    int i = bi & (Tl - 1), b = bi >> (10 - l);
    int w = 1 << l;
    const float* p1 = z1 + ((((size_t)b << 10) + ((size_t)i << l)) << 6) + c;
    const float* p2 = z2 + ((((size_t)b << 10) + ((size_t)i << l)) << 6) + c;
    float m1 = p1[0], m2 = p2[0];
    #pragma unroll 4
    for (int j = 1; j < w; j++) { m1 = fmaxf(m1, p1[(size_t)j << 6]); m2 = fmaxf(m2, p2[(size_t)j << 6]); }
    int o1 = 0, o2 = 0, zo = 0;
    #pragma unroll
    for (int q = 1; q <= 5; q++) if (l == q) { o1 = kO1[q]; o2 = kO2[q]; zo = kZOff[q]; }
    ws[o1 + k] = m1; ws[o2 + k] = m2;
    int zi = zo + ((b * 2 * Tl + i) << 6) + c;
    zcb[zi] = f2bf(m1);
    zcb[zi + (Tl << 6)] = f2bf(m2);
  } else if (idx < 1162752) {
    int kt = idx - 1146880;
    int l = 1, st = 0;
    if (kt >= 8192)  { l = 2; st = 8192; }
    if (kt >= 12288) { l = 3; st = 12288; }
    if (kt >= 14336) { l = 4; st = 14336; }
    if (kt >= 15360) { l = 5; st = 15360; }
    int k = kt - st;
    int Tl = 1024 >> l;
    int i = k & (Tl - 1), b = k >> (10 - l);
    int w = 1 << l;
    const float* pt = t + ((size_t)b << 10) + ((size_t)i << l);
    float sum = 0.f;
    #pragma unroll 4
    for (int j = 0; j < w; j++) sum += pt[j];
    int ot = 0;
    #pragma unroll
    for (int q = 1; q <= 5; q++) if (l == q) ot = kOT[q];
    ws[ot + k] = sum / (float)w;
  }
}

// ---------------- pyramid stage 2: levels 6..10 from level 5 ----------------
__global__ __launch_bounds__(256) void pyramid2_kernel(
    float* __restrict__ ws, short* __restrict__ zcb)
{
  int idx = blockIdx.x * 256 + threadIdx.x;
  const float* z15 = ws + kO1[5];
  const float* z25 = ws + kO2[5];
  const float* t5  = ws + kOT[5];
  if (idx < 31744) {
    int l = 6, st = 0;
    if (idx >= 16384) { l = 7;  st = 16384; }
    if (idx >= 24576) { l = 8;  st = 24576; }
    if (idx >= 28672) { l = 9;  st = 28672; }
    if (idx >= 30720) { l = 10; st = 30720; }
    int k = idx - st;
    int c = k & 63, bi = k >> 6;
    int Tl = 1024 >> l;
    int i = bi & (Tl - 1), b = bi >> (10 - l);
    int w = 1 << (l - 5);
    const float* p1 = z15 + ((((size_t)b << 5) + ((size_t)i << (l - 5))) << 6) + c;
    const float* p2 = z25 + ((((size_t)b << 5) + ((size_t)i << (l - 5))) << 6) + c;
    float m1 = p1[0], m2 = p2[0];
    #pragma unroll 4
    for (int j = 1; j < w; j++) { m1 = fmaxf(m1, p1[(size_t)j << 6]); m2 = fmaxf(m2, p2[(size_t)j << 6]); }
    int o1 = 0, o2 = 0, zo = 0;
    #pragma unroll
    for (int q = 6; q <= 10; q++) if (l == q) { o1 = kO1[q]; o2 = kO2[q]; zo = (q <= 9) ? kZOff[q] : -1; }
    ws[o1 + k] = m1; ws[o2 + k] = m2;
    if (l <= 9) {
      int zi = zo + ((b * 2 * Tl + i) << 6) + c;
      zcb[zi] = f2bf(m1);
      zcb[zi + (Tl << 6)] = f2bf(m2);
    }
  } else if (idx < 32240) {
    int kt = idx - 31744;
    int l = 6, st = 0;
    if (kt >= 256) { l = 7;  st = 256; }
    if (kt >= 384) { l = 8;  st = 384; }
    if (kt >= 448) { l = 9;  st = 448; }
    if (kt >= 480) { l = 10; st = 480; }
    int k = kt - st;
    int Tl = 1024 >> l;
    int i = k & (Tl - 1), b = k >> (10 - l);
    int w = 1 << (l - 5);
    const float* pt = t5 + ((size_t)b << 5) + ((size_t)i << (l - 5));
    float sum = 0.f;
    #pragma unroll
    for (int j = 0; j < w; j++) sum += pt[j];
    int ot = 0;
    #pragma unroll
    for (int q = 6; q <= 10; q++) if (l == q) ot = kOT[q];
    ws[ot + k] = sum / (float)w;
  }
}

// ---------------- fused loss (512 threads): temporal (0..575) then instance (576..1088) ----------------
__global__ __launch_bounds__(512) void loss_fused(
    const float* __restrict__ z1_0, const float* __restrict__ z2_0, const float* __restrict__ t_0,
    const float* __restrict__ ws, const short* __restrict__ zcb, float* __restrict__ out)
{
  __shared__ __align__(16) char lds[25856];   // union: temporal 2x8KB dbuf | instance state
  int bid0 = blockIdx.x;
  int tid = threadIdx.x;
  int wv = tid >> 6, lane = tid & 63, lo = lane & 15, hi = lane >> 4;

  if (bid0 < NTEMP) {
    // ================= temporal (128-row blocks, 8 waves x 16 rows, TCH=64, 1 barrier/chunk) =================
    int bid = (bid0 & 7) * 72 + (bid0 >> 3);   // bijective XCD swizzle (576 = 8*72)

    int l = 0, ls = 0;
    #pragma unroll
    for (int i = 1; i < 10; i++) if (bid >= kTS[i]) { l = i; ls = kTS[i]; }
    int T = 1024 >> l, TT = 2 * T;
    int lb = bid - ls;
    int lg = (4 - l) > 0 ? (4 - l) : 0;        // log2(128-row blocks per batch)
    int b = lb >> lg, rblk = lb & ((1 << lg) - 1);

    int zoff = 0, fo1 = 0, fo2 = 0;
    #pragma unroll
    for (int i = 1; i < 10; i++) if (l == i) { zoff = kZOff[i]; fo1 = kO1[i]; fo2 = kO2[i]; }
    const short* zl = zcb + zoff + (size_t)b * TT * C_;
    const float* z1b = ((l == 0) ? z1_0 : ws + fo1) + (size_t)b * T * C_;
    const float* z2b = ((l == 0) ? z2_0 : ws + fo2) + (size_t)b * T * C_;

    int rowbase = rblk * 128 + wv * 16;
    bool activew = rowbase < TT;
    int diagch = rowbase >> 6;

    // A fragment: one 16-row tile per wave
    int ar = rowbase + lo; if (ar >= TT) ar = TT - 1;
    const short* pa = zl + (size_t)ar * C_;
    bf16x8 a0 = *(const bf16x8*)(pa + hi * 8);
    bf16x8 a1 = *(const bf16x8*)(pa + 32 + hi * 8);

    float mb[4], s[4];                         // online LSE state, log2 units
    #pragma unroll
    for (int sl = 0; sl < 4; sl++) { mb[sl] = -POS_BIG; s[sl] = 0.f; }

    // staging: 64 rows x 128B per chunk; 1 x 16B per thread (512 threads); XOR-swizzled
    int r0 = tid >> 3, s0 = tid & 7;
    int swb0 = r0 * 128 + ((s0 * 16) ^ ((r0 & 7) << 4));

    int nch = (TT + 63) >> 6;
    float4 st0;
    {
      int q0 = r0; if (q0 >= TT) q0 = TT - 1;
      st0 = *(const float4*)(zl + (size_t)q0 * C_ + s0 * 8);
      *(float4*)(lds + swb0) = st0;
    }
    int cur = 0;

    for (int ch = 0; ch < nch; ch++) {
      __syncthreads();   // buf[cur] readable; buf[cur^1] free (prev compute done)
      if (ch + 1 < nch) {
        int nb0 = (ch + 1) * 64 + r0; if (nb0 >= TT) nb0 = TT - 1;
        st0 = *(const float4*)(zl + (size_t)nb0 * C_ + s0 * 8);
      }
      if (activew) {
        const char* base = lds + cur * 8192;
        f32x4 acc[4];
        #pragma unroll
        for (int tt = 0; tt < 4; tt++) {
          int br = tt * 16 + lo;
          int byt = br * 128 + ((hi * 16) ^ ((br & 7) << 4));
          bf16x8 b0 = *(const bf16x8*)(base + byt);
          bf16x8 b1 = *(const bf16x8*)(base + (byt ^ 64));
          f32x4 c = {0.f, 0.f, 0.f, 0.f};
          c = __builtin_amdgcn_mfma_f32_16x16x32_bf16(a0, b0, c, 0, 0, 0);
          c = __builtin_amdgcn_mfma_f32_16x16x32_bf16(a1, b1, c, 0, 0, 0);
          acc[tt] = c;
        }
        int cb = ch << 6;
        bool maskpath = (ch == diagch) || (cb + 64 > TT);
        #pragma unroll
        for (int sl = 0; sl < 4; sl++) {
          int r = rowbase + hi * 4 + sl;
          if (maskpath) {
            float v[4]; float vmax = -POS_BIG;
            #pragma unroll
            for (int tt = 0; tt < 4; tt++) {
              int cg = cb + tt * 16 + lo;
              bool excl = (cg >= TT) || (cg == r);
              v[tt] = excl ? -POS_BIG : acc[tt][sl];
              vmax = fmaxf(vmax, v[tt]);
            }
            if (vmax > -1e29f) {
              float mn = fmaxf(mb[sl], vmax * L2E);
              float ss = s[sl] * exp2f(mb[sl] - mn);
              #pragma unroll
              for (int tt = 0; tt < 4; tt++) ss += exp2f(fmaf(v[tt], L2E, -mn));
              s[sl] = ss; mb[sl] = mn;
            }
          } else {
            float v0 = acc[0][sl], v1 = acc[1][sl];
            float v2 = acc[2][sl], v3 = acc[3][sl];
            float vmax = fmaxf(fmaxf(v0, v1), fmaxf(v2, v3));
            float mn = fmaxf(mb[sl], vmax * L2E);
            float ss = s[sl] * exp2f(mb[sl] - mn);
            ss += exp2f(fmaf(v0, L2E, -mn)) + exp2f(fmaf(v1, L2E, -mn))
                + exp2f(fmaf(v2, L2E, -mn)) + exp2f(fmaf(v3, L2E, -mn));
            s[sl] = ss; mb[sl] = mn;
          }
        }
      }
      if (ch + 1 < nch) {
        char* nb = lds + (cur ^ 1) * 8192;
        *(float4*)(nb + swb0) = st0;
      }
      cur ^= 1;
    }

    // pos from f32 source (lane lo holds channels lo*4..lo*4+3)
    float pos[4];
    #pragma unroll
    for (int sl = 0; sl < 4; sl++) {
      pos[sl] = 0.f;
      int r = rowbase + hi * 4 + sl;
      if (activew && r < TT) {
        int rp = (r < T) ? r : r - T;
        float4 u = *(const float4*)(z1b + (size_t)rp * C_ + lo * 4);
        float4 v = *(const float4*)(z2b + (size_t)rp * C_ + lo * 4);
        pos[sl] = u.x * v.x + u.y * v.y + u.z * v.z + u.w * v.w;
      }
    }

    // butterfly over 16 column-subset lanes: LSE-merge (mb,s), sum pos
    #pragma unroll
    for (int msk = 1; msk < 16; msk <<= 1) {
      #pragma unroll
      for (int sl = 0; sl < 4; sl++) {
        float mo = __shfl_xor(mb[sl], msk, 16);
        float so = __shfl_xor(s[sl], msk, 16);
        float po = __shfl_xor(pos[sl], msk, 16);
        float mn = fmaxf(mb[sl], mo);
        s[sl] = s[sl] * exp2f(mb[sl] - mn) + so * exp2f(mo - mn);
        mb[sl] = mn;
        pos[sl] += po;
      }
    }

    float val = 0.f;
    if (lo == 0 && activew) {
      #pragma unroll
      for (int sl = 0; sl < 4; sl++) {
        int r = rowbase + hi * 4 + sl;
        if (r < TT) val += LN2 * (mb[sl] + __log2f(s[sl])) - pos[sl];
      }
    }
    #pragma unroll
    for (int off = 32; off; off >>= 1) val += __shfl_down(val, off, 64);
    float tscale = 0.5f / (11.0f * 2.0f * 16.0f * (float)T);
    if (lane == 0) atomicAdd(out, val * tscale);

  } else {
    // ================= instance (512 threads; r7-proven 16-lane coalesced phase B) =================
    float* dmin = (float*)lds;          // 64*17
    float* dLl  = dmin + 1088;
    float* dRl  = dLl + 1088;
    int*   Lp   = (int*)(dRl + 1088);
    int*   Rp   = Lp + 1088;
    int (*nbrs)[16] = (int(*)[16])(Rp + 1088);

    int bid = bid0 - NTEMP;
    int l = 0, ls = 0;
    #pragma unroll
    for (int i = 1; i < 11; i++) if (bid >= kIS[i]) { l = i; ls = kIS[i]; }
    int T = 1024 >> l, lgT = 10 - l, N = B_ * T;
    const float *z1, *z2, *t;
    if (l == 0) { z1 = z1_0; z2 = z2_0; t = t_0; }
    else {
      int i1 = 0, i2 = 0, it = 0;
      #pragma unroll
      for (int i = 1; i < 11; i++) if (l == i) { i1 = kO1[i]; i2 = kO2[i]; it = kOT[i]; }
      z1 = ws + i1; z2 = ws + i2; t = ws + it;
    }
    float scale = 0.5f / (11.0f * (float)N);
    int rbase = (bid - ls) * 64;

    if (T == 1) {
      for (int i2x = tid; i2x < 64 * 16; i2x += 512)
        nbrs[i2x >> 4][i2x & 15] = i2x & 15;
    } else {
      // ---- A0: 64 rows x 15 seqs parallel branchless searches ----
      for (int i2x = tid; i2x < 64 * 16; i2x += 512) {
        int r = i2x >> 4, s = i2x & 15;
        int n = rbase + r;
        if (s < 15 && n < N) {
          int bq = n >> lgT;
          float q = t[n];
          int bs = s + (s >= bq ? 1 : 0);
          const float* tb = t + (bs << lgT);
          int li = 0;
          for (int k = T >> 1; k; k >>= 1) li += (tb[li + k - 1] < q) ? k : 0;
          li += (tb[li] < q) ? 1 : 0;
          float dl = (li >= 1) ? (q - tb[li - 1]) : POS_BIG;
          float dr = (li < T)  ? (tb[li] - q)     : POS_BIG;
          int o = r * 17 + s;
          Lp[o] = li - 1; Rp[o] = li;
          dLl[o] = dl; dRl[o] = dr; dmin[o] = fminf(dl, dr);
        }
      }
    }
    __syncthreads();

    // ---- A1: per-row 16-step merge (16 lanes of waves 0..3) ----
    if (T > 1 && wv < 4 && lane < 16) {
      int r = wv * 16 + lane;
      int n = rbase + r;
      if (n < N) {
        int bq = n >> lgT;
        float q = t[n];
        #pragma unroll 1
        for (int j = 0; j < 16; j++) {
          float best = dmin[r * 17]; int sb = 0;
          #pragma unroll
          for (int s = 1; s < 15; s++) {
            float c = dmin[r * 17 + s];
            bool lt = c < best; best = lt ? c : best; sb = lt ? s : sb;
          }
          int o = r * 17 + sb;
          int bs = sb + (sb >= bq ? 1 : 0);
          float dl = dLl[o], dr = dRl[o];
          if (dl <= dr) {
            int p = Lp[o];
            nbrs[r][j] = bs * T + p;
            int pn = p - 1; Lp[o] = pn;
            float nd = (pn >= 0) ? (q - t[bs * T + pn]) : POS_BIG;
            dLl[o] = nd; dmin[o] = fminf(nd, dr);
          } else {
            int p = Rp[o];
            nbrs[r][j] = bs * T + p;
            int pn = p + 1; Rp[o] = pn;
            float nd = (pn < T) ? (t[bs * T + pn] - q) : POS_BIG;
            dRl[o] = nd; dmin[o] = fminf(dl, nd);
          }
        }
      } else {
        #pragma unroll
        for (int j = 0; j < 16; j++) nbrs[r][j] = 0;
      }
    }
    __syncthreads();

    // ---- B: wave-cooperative dots (16 lanes per row; 8 waves x 8 rows) ----
    int g = lane >> 4, sl = lane & 15;
    float loss = 0.f;
    #pragma unroll 1
    for (int rc = 0; rc < 2; rc++) {
      int r = wv * 8 + rc * 4 + g;
      int n = rbase + r;
      bool act = n < N;
      int ns = act ? n : rbase;
      float4 za = *(const float4*)(z1 + (size_t)ns * C_ + sl * 4);
      float4 zp = *(const float4*)(z2 + (size_t)ns * C_ + sl * 4);
      float pos = za.x * zp.x + za.y * zp.y + za.z * zp.z + za.w * zp.w;
      float a11[16], a12[16];
      #pragma unroll
      for (int j = 0; j < 16; j++) {
        int nb = nbrs[r][j];
        float4 uu = *(const float4*)(z1 + (size_t)nb * C_ + sl * 4);
        float4 vv = *(const float4*)(z2 + (size_t)nb * C_ + sl * 4);
        a11[j] = za.x * uu.x + za.y * uu.y + za.z * uu.z + za.w * uu.w;
        a12[j] = za.x * vv.x + za.y * vv.y + za.z * vv.z + za.w * vv.w;
      }
      #pragma unroll
      for (int msk = 1; msk < 16; msk <<= 1) {
        pos += __shfl_xor(pos, msk, 16);
        #pragma unroll
        for (int j = 0; j < 16; j++) {
          a11[j] += __shfl_xor(a11[j], msk, 16);
          a12[j] += __shfl_xor(a12[j], msk, 16);
        }
      }
      if (sl == 0 && act) {
        float m = pos;
        #pragma unroll
        for (int j = 0; j < 16; j++) m = fmaxf(m, fmaxf(a11[j], a12[j]));
        float se = __expf(pos - m);
        #pragma unroll
        for (int j = 0; j < 16; j++) se += __expf(a11[j] - m) + __expf(a12[j] - m);
        loss += (m + __logf(se)) - pos;
      }
    }
    #pragma unroll
    for (int off = 32; off; off >>= 1) loss += __shfl_down(loss, off, 64);
    if (lane == 0) atomicAdd(out, loss * scale);
  }
}

// ---------------- host side ----------------
extern "C" void kernel_launch(void* const* d_in, const int* in_sizes, int n_in,
                              void* d_out, int out_size, void* d_ws, size_t ws_size,
                              hipStream_t stream)
{
  (void)in_sizes; (void)n_in; (void)out_size; (void)ws_size;
  const float* z1_0 = (const float*)d_in[0];
  const float* z2_0 = (const float*)d_in[1];
  const float* t_0  = (const float*)d_in[2];
  float* out = (float*)d_out;
  float* ws  = (float*)d_ws;

  short* zcb = (short*)(ws + 2111472);   // bf16 zc pyramid after f32 pyramid

  hipMemsetAsync(d_out, 0, sizeof(float), stream);
  hipLaunchKernelGGL(pyramid1_kernel, dim3(4542), dim3(256), 0, stream,
                     z1_0, z2_0, t_0, ws, zcb);
  hipLaunchKernelGGL(pyramid2_kernel, dim3(126), dim3(256), 0, stream, ws, zcb);
  hipLaunchKernelGGL(loss_fused, dim3(NTEMP + NINST), dim3(512), 0, stream,
                     z1_0, z2_0, t_0, ws, zcb, out);
}

// Round 15
// 142.970 us; speedup vs baseline: 1.1722x; 1.1722x over previous
//
#include <hip/hip_runtime.h>
#include <hip/hip_bf16.h>
#include <math.h>

#define B_ 16
#define C_ 64
#define POS_BIG (1e30f)
#define L2E 1.44269504088896340736f
#define LN2 0.69314718055994530942f

typedef __attribute__((ext_vector_type(8))) short bf16x8;
typedef __attribute__((ext_vector_type(4))) float f32x4;

__device__ __forceinline__ short f2bf(float x) {
  __hip_bfloat16 h = __float2bfloat16(x);
  return *reinterpret_cast<short*>(&h);
}

// ---- compile-time tables (fixed problem B=16, T=1024, C=64) ----
// temporal: 576 blocks (128 rows each); starts per level l=0..9
__device__ constexpr int kTS[10]   = {0, 256, 384, 448, 480, 496, 512, 528, 544, 560};
__device__ constexpr int kZOff[10] = {0, 2097152, 3145728, 3670016, 3932160, 4063232,
                                      4128768, 4161536, 4177920, 4186112};               // shorts
// instance: 513 blocks; starts per level l=0..10
__device__ constexpr int kIS[11] = {0, 256, 384, 448, 480, 496, 504, 508, 510, 511, 512};
// f32 pyramid offsets in ws (floats), l=1..10
__device__ constexpr int kO1[11] = {0, 0, 1056768, 1585152, 1849344, 1981440, 2047488,
                                    2080512, 2097024, 2105280, 2109408};
__device__ constexpr int kO2[11] = {0, 524288, 1318912, 1716224, 1914880, 2014208, 2063872,
                                    2088704, 2101120, 2107328, 2110432};
__device__ constexpr int kOT[11] = {0, 1048576, 1581056, 1847296, 1980416, 2046976, 2080256,
                                    2096896, 2105216, 2109376, 2111456};

#define NTEMP 576
#define NINST 513

// ---------------- pyramid stage 1: L0 bf16 convert + levels 1..5 direct from L0 ----------------
__global__ __launch_bounds__(256) void pyramid1_kernel(
    const float* __restrict__ z1, const float* __restrict__ z2, const float* __restrict__ t,
    float* __restrict__ ws, short* __restrict__ zcb)
{
  int idx = blockIdx.x * 256 + threadIdx.x;
  if (idx < 131072) {
    int n = idx * 8;
    int b = n >> 16;
    float4 u1 = *(const float4*)(z1 + n), v1 = *(const float4*)(z1 + n + 4);
    float4 u2 = *(const float4*)(z2 + n), v2 = *(const float4*)(z2 + n + 4);
    bf16x8 f1, f2;
    f1[0]=f2bf(u1.x); f1[1]=f2bf(u1.y); f1[2]=f2bf(u1.z); f1[3]=f2bf(u1.w);
    f1[4]=f2bf(v1.x); f1[5]=f2bf(v1.y); f1[6]=f2bf(v1.z); f1[7]=f2bf(v1.w);
    f2[0]=f2bf(u2.x); f2[1]=f2bf(u2.y); f2[2]=f2bf(u2.z); f2[3]=f2bf(u2.w);
    f2[4]=f2bf(v2.x); f2[5]=f2bf(v2.y); f2[6]=f2bf(v2.z); f2[7]=f2bf(v2.w);
    *(bf16x8*)(zcb + (size_t)n + (size_t)b * 65536) = f1;
    *(bf16x8*)(zcb + (size_t)n + (size_t)(b + 1) * 65536) = f2;
  } else if (idx < 1146880) {
    int li = idx - 131072;
    int l = 1, st = 0;
    if (li >= 524288) { l = 2; st = 524288; }
    if (li >= 786432) { l = 3; st = 786432; }
    if (li >= 917504) { l = 4; st = 917504; }
    if (li >= 983040) { l = 5; st = 983040; }
    int k = li - st;
    int c = k & 63, bi = k >> 6;
    int Tl = 1024 >> l;
    int i = bi & (Tl - 1), b = bi >> (10 - l);
    int w = 1 << l;
    const float* p1 = z1 + ((((size_t)b << 10) + ((size_t)i << l)) << 6) + c;
    const float* p2 = z2 + ((((size_t)b << 10) + ((size_t)i << l)) << 6) + c;
    float m1 = p1[0], m2 = p2[0];
    #pragma unroll 4
    for (int j = 1; j < w; j++) { m1 = fmaxf(m1, p1[(size_t)j << 6]); m2 = fmaxf(m2, p2[(size_t)j << 6]); }
    int o1 = 0, o2 = 0, zo = 0;
    #pragma unroll
    for (int q = 1; q <= 5; q++) if (l == q) { o1 = kO1[q]; o2 = kO2[q]; zo = kZOff[q]; }
    ws[o1 + k] = m1; ws[o2 + k] = m2;
    int zi = zo + ((b * 2 * Tl + i) << 6) + c;
    zcb[zi] = f2bf(m1);
    zcb[zi + (Tl << 6)] = f2bf(m2);
  } else if (idx < 1162752) {
    int kt = idx - 1146880;
    int l = 1, st = 0;
    if (kt >= 8192)  { l = 2; st = 8192; }
    if (kt >= 12288) { l = 3; st = 12288; }
    if (kt >= 14336) { l = 4; st = 14336; }
    if (kt >= 15360) { l = 5; st = 15360; }
    int k = kt - st;
    int Tl = 1024 >> l;
    int i = k & (Tl - 1), b = k >> (10 - l);
    int w = 1 << l;
    const float* pt = t + ((size_t)b << 10) + ((size_t)i << l);
    float sum = 0.f;
    #pragma unroll 4
    for (int j = 0; j < w; j++) sum += pt[j];
    int ot = 0;
    #pragma unroll
    for (int q = 1; q <= 5; q++) if (l == q) ot = kOT[q];
    ws[ot + k] = sum / (float)w;
  }
}

// ---------------- pyramid stage 2: levels 6..10 from level 5 ----------------
__global__ __launch_bounds__(256) void pyramid2_kernel(
    float* __restrict__ ws, short* __restrict__ zcb)
{
  int idx = blockIdx.x * 256 + threadIdx.x;
  const float* z15 = ws + kO1[5];
  const float* z25 = ws + kO2[5];
  const float* t5  = ws + kOT[5];
  if (idx < 31744) {
    int l = 6, st = 0;
    if (idx >= 16384) { l = 7;  st = 16384; }
    if (idx >= 24576) { l = 8;  st = 24576; }
    if (idx >= 28672) { l = 9;  st = 28672; }
    if (idx >= 30720) { l = 10; st = 30720; }
    int k = idx - st;
    int c = k & 63, bi = k >> 6;
    int Tl = 1024 >> l;
    int i = bi & (Tl - 1), b = bi >> (10 - l);
    int w = 1 << (l - 5);
    const float* p1 = z15 + ((((size_t)b << 5) + ((size_t)i << (l - 5))) << 6) + c;
    const float* p2 = z25 + ((((size_t)b << 5) + ((size_t)i << (l - 5))) << 6) + c;
    float m1 = p1[0], m2 = p2[0];
    #pragma unroll 4
    for (int j = 1; j < w; j++) { m1 = fmaxf(m1, p1[(size_t)j << 6]); m2 = fmaxf(m2, p2[(size_t)j << 6]); }
    int o1 = 0, o2 = 0, zo = 0;
    #pragma unroll
    for (int q = 6; q <= 10; q++) if (l == q) { o1 = kO1[q]; o2 = kO2[q]; zo = (q <= 9) ? kZOff[q] : -1; }
    ws[o1 + k] = m1; ws[o2 + k] = m2;
    if (l <= 9) {
      int zi = zo + ((b * 2 * Tl + i) << 6) + c;
      zcb[zi] = f2bf(m1);
      zcb[zi + (Tl << 6)] = f2bf(m2);
    }
  } else if (idx < 32240) {
    int kt = idx - 31744;
    int l = 6, st = 0;
    if (kt >= 256) { l = 7;  st = 256; }
    if (kt >= 384) { l = 8;  st = 384; }
    if (kt >= 448) { l = 9;  st = 448; }
    if (kt >= 480) { l = 10; st = 480; }
    int k = kt - st;
    int Tl = 1024 >> l;
    int i = k & (Tl - 1), b = k >> (10 - l);
    int w = 1 << (l - 5);
    const float* pt = t5 + ((size_t)b << 5) + ((size_t)i << (l - 5));
    float sum = 0.f;
    #pragma unroll
    for (int j = 0; j < w; j++) sum += pt[j];
    int ot = 0;
    #pragma unroll
    for (int q = 6; q <= 10; q++) if (l == q) ot = kOT[q];
    ws[ot + k] = sum / (float)w;
  }
}

// ---------------- fused loss: temporal (0..575) then instance (576..1088) ----------------
__global__ __launch_bounds__(256) void loss_fused(
    const float* __restrict__ z1_0, const float* __restrict__ z2_0, const float* __restrict__ t_0,
    const float* __restrict__ ws, const short* __restrict__ zcb, float* __restrict__ out)
{
  __shared__ __align__(16) char lds[32768];   // union: temporal 2x16KB dbuf | instance 25856B
  int bid0 = blockIdx.x;
  int tid = threadIdx.x;
  int wv = tid >> 6, lane = tid & 63, lo = lane & 15, hi = lane >> 4;

  if (bid0 < NTEMP) {
    // ========== temporal: 128 rows, 4 waves, 128-col chunk per barrier, 2 x 64-col halves ==========
    int bid = (bid0 & 7) * 72 + (bid0 >> 3);   // bijective XCD swizzle (576 = 8*72)

    int l = 0, ls = 0;
    #pragma unroll
    for (int i = 1; i < 10; i++) if (bid >= kTS[i]) { l = i; ls = kTS[i]; }
    int T = 1024 >> l, TT = 2 * T;
    int lb = bid - ls;
    int lg = (4 - l) > 0 ? (4 - l) : 0;        // log2(128-row blocks per batch)
    int b = lb >> lg, rblk = lb & ((1 << lg) - 1);

    int zoff = 0, fo1 = 0, fo2 = 0;
    #pragma unroll
    for (int i = 1; i < 10; i++) if (l == i) { zoff = kZOff[i]; fo1 = kO1[i]; fo2 = kO2[i]; }
    const short* zl = zcb + zoff + (size_t)b * TT * C_;
    const float* z1b = ((l == 0) ? z1_0 : ws + fo1) + (size_t)b * T * C_;
    const float* z2b = ((l == 0) ? z2_0 : ws + fo2) + (size_t)b * T * C_;

    int rowbase = rblk * 128 + wv * 32;
    bool activew = rowbase < TT;
    int diagch = rowbase >> 6;                 // 64-col diag block index

    // A fragments: 2 row-tiles of 16
    bf16x8 a0[2], a1[2];
    #pragma unroll
    for (int rt = 0; rt < 2; rt++) {
      int ar = rowbase + rt * 16 + lo; if (ar >= TT) ar = TT - 1;
      const short* pa = zl + (size_t)ar * C_;
      a0[rt] = *(const bf16x8*)(pa + hi * 8);
      a1[rt] = *(const bf16x8*)(pa + 32 + hi * 8);
    }

    float mb[2][4], s[2][4];                   // online LSE state, log2 units
    #pragma unroll
    for (int rt = 0; rt < 2; rt++)
      #pragma unroll
      for (int sl = 0; sl < 4; sl++) { mb[rt][sl] = -POS_BIG; s[rt][sl] = 0.f; }

    // staging: 128 rows x 128B per chunk; 4 x 16B per thread; XOR-swizzled
    int r0 = tid >> 3, s0 = tid & 7;
    int swb[4];
    #pragma unroll
    for (int k = 0; k < 4; k++) {
      int rr = r0 + 32 * k;
      swb[k] = rr * 128 + ((s0 * 16) ^ ((rr & 7) << 4));
    }

    int nch = (TT + 127) >> 7;
    float4 st[4];
    { // prologue: load + write chunk 0 into buf 0
      #pragma unroll
      for (int k = 0; k < 4; k++) {
        int q = r0 + 32 * k; if (q >= TT) q = TT - 1;
        st[k] = *(const float4*)(zl + (size_t)q * C_ + s0 * 8);
        *(float4*)(lds + swb[k]) = st[k];
      }
    }
    int cur = 0;

    for (int ch = 0; ch < nch; ch++) {
      __syncthreads();   // buf[cur] readable; buf[cur^1] free (prev compute done)
      if (ch + 1 < nch) {
        #pragma unroll
        for (int k = 0; k < 4; k++) {
          int nb = (ch + 1) * 128 + r0 + 32 * k; if (nb >= TT) nb = TT - 1;
          st[k] = *(const float4*)(zl + (size_t)nb * C_ + s0 * 8);
        }
      }
      if (activew) {
        const char* base = lds + cur * 16384;
        #pragma unroll
        for (int half = 0; half < 2; half++) {
          int cb = (ch << 7) + (half << 6);
          if (cb < TT) {
            f32x4 acc[2][4];
            #pragma unroll
            for (int tt = 0; tt < 4; tt++) {
              int br = (half << 6) + tt * 16 + lo;
              int byt = br * 128 + ((hi * 16) ^ ((br & 7) << 4));
              bf16x8 b0 = *(const bf16x8*)(base + byt);
              bf16x8 b1 = *(const bf16x8*)(base + (byt ^ 64));
              #pragma unroll
              for (int rt = 0; rt < 2; rt++) {
                f32x4 c = {0.f, 0.f, 0.f, 0.f};
                c = __builtin_amdgcn_mfma_f32_16x16x32_bf16(a0[rt], b0, c, 0, 0, 0);
                c = __builtin_amdgcn_mfma_f32_16x16x32_bf16(a1[rt], b1, c, 0, 0, 0);
                acc[rt][tt] = c;
              }
            }
            bool maskpath = ((cb >> 6) == diagch) || (cb + 64 > TT);
            #pragma unroll
            for (int rt = 0; rt < 2; rt++) {
              #pragma unroll
              for (int sl = 0; sl < 4; sl++) {
                int r = rowbase + rt * 16 + hi * 4 + sl;
                if (maskpath) {
                  float v[4]; float vmax = -POS_BIG;
                  #pragma unroll
                  for (int tt = 0; tt < 4; tt++) {
                    int cg = cb + tt * 16 + lo;
                    bool excl = (cg >= TT) || (cg == r);
                    v[tt] = excl ? -POS_BIG : acc[rt][tt][sl];
                    vmax = fmaxf(vmax, v[tt]);
                  }
                  if (vmax > -1e29f) {
                    float mn = fmaxf(mb[rt][sl], vmax * L2E);
                    float ss = s[rt][sl] * exp2f(mb[rt][sl] - mn);
                    #pragma unroll
                    for (int tt = 0; tt < 4; tt++) ss += exp2f(fmaf(v[tt], L2E, -mn));
                    s[rt][sl] = ss; mb[rt][sl] = mn;
                  }
                } else {
                  float v0 = acc[rt][0][sl], v1 = acc[rt][1][sl];
                  float v2 = acc[rt][2][sl], v3 = acc[rt][3][sl];
                  float vmax = fmaxf(fmaxf(v0, v1), fmaxf(v2, v3));
                  float mn = fmaxf(mb[rt][sl], vmax * L2E);
                  float ss = s[rt][sl] * exp2f(mb[rt][sl] - mn);
                  ss += exp2f(fmaf(v0, L2E, -mn)) + exp2f(fmaf(v1, L2E, -mn))
                      + exp2f(fmaf(v2, L2E, -mn)) + exp2f(fmaf(v3, L2E, -mn));
                  s[rt][sl] = ss; mb[rt][sl] = mn;
                }
              }
            }
          }
        }
      }
      if (ch + 1 < nch) {
        char* nb = lds + (cur ^ 1) * 16384;
        #pragma unroll
        for (int k = 0; k < 4; k++) *(float4*)(nb + swb[k]) = st[k];
      }
      cur ^= 1;
    }

    // pos from f32 source (lane lo holds channels lo*4..lo*4+3)
    float pos[2][4];
    #pragma unroll
    for (int rt = 0; rt < 2; rt++) {
      #pragma unroll
      for (int sl = 0; sl < 4; sl++) {
        pos[rt][sl] = 0.f;
        int r = rowbase + rt * 16 + hi * 4 + sl;
        if (activew && r < TT) {
          int rp = (r < T) ? r : r - T;
          float4 u = *(const float4*)(z1b + (size_t)rp * C_ + lo * 4);
          float4 v = *(const float4*)(z2b + (size_t)rp * C_ + lo * 4);
          pos[rt][sl] = u.x * v.x + u.y * v.y + u.z * v.z + u.w * v.w;
        }
      }
    }

    // butterfly over 16 column-subset lanes: LSE-merge (mb,s), sum pos
    #pragma unroll
    for (int msk = 1; msk < 16; msk <<= 1) {
      #pragma unroll
      for (int rt = 0; rt < 2; rt++) {
        #pragma unroll
        for (int sl = 0; sl < 4; sl++) {
          float mo = __shfl_xor(mb[rt][sl], msk, 16);
          float so = __shfl_xor(s[rt][sl], msk, 16);
          float po = __shfl_xor(pos[rt][sl], msk, 16);
          float mn = fmaxf(mb[rt][sl], mo);
          s[rt][sl] = s[rt][sl] * exp2f(mb[rt][sl] - mn) + so * exp2f(mo - mn);
          mb[rt][sl] = mn;
          pos[rt][sl] += po;
        }
      }
    }

    float val = 0.f;
    if (lo == 0 && activew) {
      #pragma unroll
      for (int rt = 0; rt < 2; rt++) {
        #pragma unroll
        for (int sl = 0; sl < 4; sl++) {
          int r = rowbase + rt * 16 + hi * 4 + sl;
          if (r < TT) val += LN2 * (mb[rt][sl] + __log2f(s[rt][sl])) - pos[rt][sl];
        }
      }
    }
    #pragma unroll
    for (int off = 32; off; off >>= 1) val += __shfl_down(val, off, 64);
    float tscale = 0.5f / (11.0f * 2.0f * 16.0f * (float)T);
    if (lane == 0) atomicAdd(out, val * tscale);

  } else {
    // ================= instance (r7/r11-proven: 16-lane coalesced phase B) =================
    float* dmin = (float*)lds;          // 64*17
    float* dLl  = dmin + 1088;
    float* dRl  = dLl + 1088;
    int*   Lp   = (int*)(dRl + 1088);
    int*   Rp   = Lp + 1088;
    int (*nbrs)[16] = (int(*)[16])(Rp + 1088);

    int bid = bid0 - NTEMP;
    int l = 0, ls = 0;
    #pragma unroll
    for (int i = 1; i < 11; i++) if (bid >= kIS[i]) { l = i; ls = kIS[i]; }
    int T = 1024 >> l, lgT = 10 - l, N = B_ * T;
    const float *z1, *z2, *t;
    if (l == 0) { z1 = z1_0; z2 = z2_0; t = t_0; }
    else {
      int i1 = 0, i2 = 0, it = 0;
      #pragma unroll
      for (int i = 1; i < 11; i++) if (l == i) { i1 = kO1[i]; i2 = kO2[i]; it = kOT[i]; }
      z1 = ws + i1; z2 = ws + i2; t = ws + it;
    }
    float scale = 0.5f / (11.0f * (float)N);
    int rbase = (bid - ls) * 64;

    if (T == 1) {
      for (int i2x = tid; i2x < 64 * 16; i2x += 256)
        nbrs[i2x >> 4][i2x & 15] = i2x & 15;
    } else {
      // ---- A0: 64 rows x 15 seqs parallel branchless searches ----
      for (int i2x = tid; i2x < 64 * 16; i2x += 256) {
        int r = i2x >> 4, s = i2x & 15;
        int n = rbase + r;
        if (s < 15 && n < N) {
          int bq = n >> lgT;
          float q = t[n];
          int bs = s + (s >= bq ? 1 : 0);
          const float* tb = t + (bs << lgT);
          int li = 0;
          for (int k = T >> 1; k; k >>= 1) li += (tb[li + k - 1] < q) ? k : 0;
          li += (tb[li] < q) ? 1 : 0;
          float dl = (li >= 1) ? (q - tb[li - 1]) : POS_BIG;
          float dr = (li < T)  ? (tb[li] - q)     : POS_BIG;
          int o = r * 17 + s;
          Lp[o] = li - 1; Rp[o] = li;
          dLl[o] = dl; dRl[o] = dr; dmin[o] = fminf(dl, dr);
        }
      }
    }
    __syncthreads();

    // ---- A1: per-row 16-step merge (16 lanes of each wave) ----
    if (T > 1 && lane < 16) {
      int r = wv * 16 + lane;
      int n = rbase + r;
      if (n < N) {
        int bq = n >> lgT;
        float q = t[n];
        #pragma unroll 1
        for (int j = 0; j < 16; j++) {
          float best = dmin[r * 17]; int sb = 0;
          #pragma unroll
          for (int s = 1; s < 15; s++) {
            float c = dmin[r * 17 + s];
            bool lt = c < best; best = lt ? c : best; sb = lt ? s : sb;
          }
          int o = r * 17 + sb;
          int bs = sb + (sb >= bq ? 1 : 0);
          float dl = dLl[o], dr = dRl[o];
          if (dl <= dr) {
            int p = Lp[o];
            nbrs[r][j] = bs * T + p;
            int pn = p - 1; Lp[o] = pn;
            float nd = (pn >= 0) ? (q - t[bs * T + pn]) : POS_BIG;
            dLl[o] = nd; dmin[o] = fminf(nd, dr);
          } else {
            int p = Rp[o];
            nbrs[r][j] = bs * T + p;
            int pn = p + 1; Rp[o] = pn;
            float nd = (pn < T) ? (t[bs * T + pn] - q) : POS_BIG;
            dRl[o] = nd; dmin[o] = fminf(dl, nd);
          }
        }
      } else {
        #pragma unroll
        for (int j = 0; j < 16; j++) nbrs[r][j] = 0;
      }
    }
    __syncthreads();

    // ---- B: wave-cooperative dots (16 lanes per row, coalesced 256B rows) ----
    int g = lane >> 4, sl = lane & 15;
    float loss = 0.f;
    #pragma unroll 1
    for (int rc = 0; rc < 4; rc++) {
      int r = wv * 16 + rc * 4 + g;
      int n = rbase + r;
      bool act = n < N;
      int ns = act ? n : rbase;
      float4 za = *(const float4*)(z1 + (size_t)ns * C_ + sl * 4);
      float4 zp = *(const float4*)(z2 + (size_t)ns * C_ + sl * 4);
      float pos = za.x * zp.x + za.y * zp.y + za.z * zp.z + za.w * zp.w;
      float a11[16], a12[16];
      #pragma unroll
      for (int j = 0; j < 16; j++) {
        int nb = nbrs[r][j];
        float4 uu = *(const float4*)(z1 + (size_t)nb * C_ + sl * 4);
        float4 vv = *(const float4*)(z2 + (size_t)nb * C_ + sl * 4);
        a11[j] = za.x * uu.x + za.y * uu.y + za.z * uu.z + za.w * uu.w;
        a12[j] = za.x * vv.x + za.y * vv.y + za.z * vv.z + za.w * vv.w;
      }
      #pragma unroll
      for (int msk = 1; msk < 16; msk <<= 1) {
        pos += __shfl_xor(pos, msk, 16);
        #pragma unroll
        for (int j = 0; j < 16; j++) {
          a11[j] += __shfl_xor(a11[j], msk, 16);
          a12[j] += __shfl_xor(a12[j], msk, 16);
        }
      }
      if (sl == 0 && act) {
        float m = pos;
        #pragma unroll
        for (int j = 0; j < 16; j++) m = fmaxf(m, fmaxf(a11[j], a12[j]));
        float se = __expf(pos - m);
        #pragma unroll
        for (int j = 0; j < 16; j++) se += __expf(a11[j] - m) + __expf(a12[j] - m);
        loss += (m + __logf(se)) - pos;
      }
    }
    #pragma unroll
    for (int off = 32; off; off >>= 1) loss += __shfl_down(loss, off, 64);
    if (lane == 0) atomicAdd(out, loss * scale);
  }
}

// ---------------- host side ----------------
extern "C" void kernel_launch(void* const* d_in, const int* in_sizes, int n_in,
                              void* d_out, int out_size, void* d_ws, size_t ws_size,
                              hipStream_t stream)
{
  (void)in_sizes; (void)n_in; (void)out_size; (void)ws_size;
  const float* z1_0 = (const float*)d_in[0];
  const float* z2_0 = (const float*)d_in[1];
  const float* t_0  = (const float*)d_in[2];
  float* out = (float*)d_out;
  float* ws  = (float*)d_ws;

  short* zcb = (short*)(ws + 2111472);   // bf16 zc pyramid after f32 pyramid

  hipMemsetAsync(d_out, 0, sizeof(float), stream);
  hipLaunchKernelGGL(pyramid1_kernel, dim3(4542), dim3(256), 0, stream,
                     z1_0, z2_0, t_0, ws, zcb);
  hipLaunchKernelGGL(pyramid2_kernel, dim3(126), dim3(256), 0, stream, ws, zcb);
  hipLaunchKernelGGL(loss_fused, dim3(NTEMP + NINST), dim3(256), 0, stream,
                     z1_0, z2_0, t_0, ws, zcb, out);
}

// Round 16
// 142.186 us; speedup vs baseline: 1.1786x; 1.0055x over previous
//
#include <hip/hip_runtime.h>
#include <hip/hip_bf16.h>
#include <math.h>

#define B_ 16
#define C_ 64
#define POS_BIG (1e30f)
#define L2E 1.44269504088896340736f
#define LN2 0.69314718055994530942f

typedef __attribute__((ext_vector_type(8))) short bf16x8;
typedef __attribute__((ext_vector_type(4))) float f32x4;

__device__ __forceinline__ short f2bf(float x) {
  __hip_bfloat16 h = __float2bfloat16(x);
  return *reinterpret_cast<short*>(&h);
}
__device__ __forceinline__ float b2f(unsigned short u) {
  return __uint_as_float((unsigned)u << 16);
}

// ---- compile-time tables (fixed problem B=16, T=1024, C=64) ----
// temporal: 576 blocks (128 rows each); starts per level l=0..9
__device__ constexpr int kTS[10]   = {0, 256, 384, 448, 480, 496, 512, 528, 544, 560};
__device__ constexpr int kZOff[10] = {0, 2097152, 3145728, 3670016, 3932160, 4063232,
                                      4128768, 4161536, 4177920, 4186112};               // shorts
// instance: 513 blocks; starts per level l=0..10
__device__ constexpr int kIS[11] = {0, 256, 384, 448, 480, 496, 504, 508, 510, 511, 512};
// f32 pyramid offsets in ws (floats), l=1..10
__device__ constexpr int kO1[11] = {0, 0, 1056768, 1585152, 1849344, 1981440, 2047488,
                                    2080512, 2097024, 2105280, 2109408};
__device__ constexpr int kO2[11] = {0, 524288, 1318912, 1716224, 1914880, 2014208, 2063872,
                                    2088704, 2101120, 2107328, 2110432};
__device__ constexpr int kOT[11] = {0, 1048576, 1581056, 1847296, 1980416, 2046976, 2080256,
                                    2096896, 2105216, 2109376, 2111456};

#define NTEMP 576
#define NINST 513

// ---------------- pyramid stage 1: L0 bf16 convert + levels 1..5 direct from L0 ----------------
__global__ __launch_bounds__(256) void pyramid1_kernel(
    const float* __restrict__ z1, const float* __restrict__ z2, const float* __restrict__ t,
    float* __restrict__ ws, short* __restrict__ zcb)
{
  int idx = blockIdx.x * 256 + threadIdx.x;
  if (idx < 131072) {
    int n = idx * 8;
    int b = n >> 16;
    float4 u1 = *(const float4*)(z1 + n), v1 = *(const float4*)(z1 + n + 4);
    float4 u2 = *(const float4*)(z2 + n), v2 = *(const float4*)(z2 + n + 4);
    bf16x8 f1, f2;
    f1[0]=f2bf(u1.x); f1[1]=f2bf(u1.y); f1[2]=f2bf(u1.z); f1[3]=f2bf(u1.w);
    f1[4]=f2bf(v1.x); f1[5]=f2bf(v1.y); f1[6]=f2bf(v1.z); f1[7]=f2bf(v1.w);
    f2[0]=f2bf(u2.x); f2[1]=f2bf(u2.y); f2[2]=f2bf(u2.z); f2[3]=f2bf(u2.w);
    f2[4]=f2bf(v2.x); f2[5]=f2bf(v2.y); f2[6]=f2bf(v2.z); f2[7]=f2bf(v2.w);
    *(bf16x8*)(zcb + (size_t)n + (size_t)b * 65536) = f1;
    *(bf16x8*)(zcb + (size_t)n + (size_t)(b + 1) * 65536) = f2;
  } else if (idx < 1146880) {
    int li = idx - 131072;
    int l = 1, st = 0;
    if (li >= 524288) { l = 2; st = 524288; }
    if (li >= 786432) { l = 3; st = 786432; }
    if (li >= 917504) { l = 4; st = 917504; }
    if (li >= 983040) { l = 5; st = 983040; }
    int k = li - st;
    int c = k & 63, bi = k >> 6;
    int Tl = 1024 >> l;
    int i = bi & (Tl - 1), b = bi >> (10 - l);
    int w = 1 << l;
    const float* p1 = z1 + ((((size_t)b << 10) + ((size_t)i << l)) << 6) + c;
    const float* p2 = z2 + ((((size_t)b << 10) + ((size_t)i << l)) << 6) + c;
    float m1 = p1[0], m2 = p2[0];
    #pragma unroll 4
    for (int j = 1; j < w; j++) { m1 = fmaxf(m1, p1[(size_t)j << 6]); m2 = fmaxf(m2, p2[(size_t)j << 6]); }
    int o1 = 0, o2 = 0, zo = 0;
    #pragma unroll
    for (int q = 1; q <= 5; q++) if (l == q) { o1 = kO1[q]; o2 = kO2[q]; zo = kZOff[q]; }
    ws[o1 + k] = m1; ws[o2 + k] = m2;
    int zi = zo + ((b * 2 * Tl + i) << 6) + c;
    zcb[zi] = f2bf(m1);
    zcb[zi + (Tl << 6)] = f2bf(m2);
  } else if (idx < 1162752) {
    int kt = idx - 1146880;
    int l = 1, st = 0;
    if (kt >= 8192)  { l = 2; st = 8192; }
    if (kt >= 12288) { l = 3; st = 12288; }
    if (kt >= 14336) { l = 4; st = 14336; }
    if (kt >= 15360) { l = 5; st = 15360; }
    int k = kt - st;
    int Tl = 1024 >> l;
    int i = k & (Tl - 1), b = k >> (10 - l);
    int w = 1 << l;
    const float* pt = t + ((size_t)b << 10) + ((size_t)i << l);
    float sum = 0.f;
    #pragma unroll 4
    for (int j = 0; j < w; j++) sum += pt[j];
    int ot = 0;
    #pragma unroll
    for (int q = 1; q <= 5; q++) if (l == q) ot = kOT[q];
    ws[ot + k] = sum / (float)w;
  }
}

// ---------------- pyramid stage 2: levels 6..10 from level 5 ----------------
__global__ __launch_bounds__(256) void pyramid2_kernel(
    float* __restrict__ ws, short* __restrict__ zcb)
{
  int idx = blockIdx.x * 256 + threadIdx.x;
  const float* z15 = ws + kO1[5];
  const float* z25 = ws + kO2[5];
  const float* t5  = ws + kOT[5];
  if (idx < 31744) {
    int l = 6, st = 0;
    if (idx >= 16384) { l = 7;  st = 16384; }
    if (idx >= 24576) { l = 8;  st = 24576; }
    if (idx >= 28672) { l = 9;  st = 28672; }
    if (idx >= 30720) { l = 10; st = 30720; }
    int k = idx - st;
    int c = k & 63, bi = k >> 6;
    int Tl = 1024 >> l;
    int i = bi & (Tl - 1), b = bi >> (10 - l);
    int w = 1 << (l - 5);
    const float* p1 = z15 + ((((size_t)b << 5) + ((size_t)i << (l - 5))) << 6) + c;
    const float* p2 = z25 + ((((size_t)b << 5) + ((size_t)i << (l - 5))) << 6) + c;
    float m1 = p1[0], m2 = p2[0];
    #pragma unroll 4
    for (int j = 1; j < w; j++) { m1 = fmaxf(m1, p1[(size_t)j << 6]); m2 = fmaxf(m2, p2[(size_t)j << 6]); }
    int o1 = 0, o2 = 0, zo = 0;
    #pragma unroll
    for (int q = 6; q <= 10; q++) if (l == q) { o1 = kO1[q]; o2 = kO2[q]; zo = (q <= 9) ? kZOff[q] : -1; }
    ws[o1 + k] = m1; ws[o2 + k] = m2;
    if (l <= 9) {
      int zi = zo + ((b * 2 * Tl + i) << 6) + c;
      zcb[zi] = f2bf(m1);
      zcb[zi + (Tl << 6)] = f2bf(m2);
    }
  } else if (idx < 32240) {
    int kt = idx - 31744;
    int l = 6, st = 0;
    if (kt >= 256) { l = 7;  st = 256; }
    if (kt >= 384) { l = 8;  st = 384; }
    if (kt >= 448) { l = 9;  st = 448; }
    if (kt >= 480) { l = 10; st = 480; }
    int k = kt - st;
    int Tl = 1024 >> l;
    int i = k & (Tl - 1), b = k >> (10 - l);
    int w = 1 << (l - 5);
    const float* pt = t5 + ((size_t)b << 5) + ((size_t)i << (l - 5));
    float sum = 0.f;
    #pragma unroll
    for (int j = 0; j < w; j++) sum += pt[j];
    int ot = 0;
    #pragma unroll
    for (int q = 6; q <= 10; q++) if (l == q) ot = kOT[q];
    ws[ot + k] = sum / (float)w;
  }
}

// ---------------- fused loss: temporal (blocks 0..575) then instance (blocks 576..1088) ----------------
__global__ __launch_bounds__(256) void loss_fused(
    const float* __restrict__ z1_0, const float* __restrict__ z2_0, const float* __restrict__ t_0,
    const float* __restrict__ ws, const short* __restrict__ zcb, float* __restrict__ out)
{
  __shared__ __align__(16) char lds[25856];   // union: temporal 2x8KB dbuf | instance state
  int bid0 = blockIdx.x;
  int tid = threadIdx.x;
  int wv = tid >> 6, lane = tid & 63, lo = lane & 15, hi = lane >> 4;

  if (bid0 < NTEMP) {
    // ================= temporal (r11-proven: 128 rows, 4 waves, TCH=64, 1 barrier/chunk) =================
    int bid = (bid0 & 7) * 72 + (bid0 >> 3);   // bijective XCD swizzle (576 = 8*72)

    int l = 0, ls = 0;
    #pragma unroll
    for (int i = 1; i < 10; i++) if (bid >= kTS[i]) { l = i; ls = kTS[i]; }
    int T = 1024 >> l, TT = 2 * T;
    int lb = bid - ls;
    int lg = (4 - l) > 0 ? (4 - l) : 0;        // log2(128-row blocks per batch)
    int b = lb >> lg, rblk = lb & ((1 << lg) - 1);

    int zoff = 0, fo1 = 0, fo2 = 0;
    #pragma unroll
    for (int i = 1; i < 10; i++) if (l == i) { zoff = kZOff[i]; fo1 = kO1[i]; fo2 = kO2[i]; }
    const short* zl = zcb + zoff + (size_t)b * TT * C_;
    const float* z1b = ((l == 0) ? z1_0 : ws + fo1) + (size_t)b * T * C_;
    const float* z2b = ((l == 0) ? z2_0 : ws + fo2) + (size_t)b * T * C_;

    int rowbase = rblk * 128 + wv * 32;
    bool activew = rowbase < TT;
    int diagch = rowbase >> 6;

    bf16x8 a0[2], a1[2];
    #pragma unroll
    for (int rt = 0; rt < 2; rt++) {
      int ar = rowbase + rt * 16 + lo; if (ar >= TT) ar = TT - 1;
      const short* pa = zl + (size_t)ar * C_;
      a0[rt] = *(const bf16x8*)(pa + hi * 8);
      a1[rt] = *(const bf16x8*)(pa + 32 + hi * 8);
    }

    float mb[2][4], s[2][4];                   // online LSE state, log2 units
    #pragma unroll
    for (int rt = 0; rt < 2; rt++)
      #pragma unroll
      for (int sl = 0; sl < 4; sl++) { mb[rt][sl] = -POS_BIG; s[rt][sl] = 0.f; }

    int r0 = tid >> 3, s0 = tid & 7;
    int r1 = r0 + 32, s1v = s0;
    int swb0 = r0 * 128 + ((s0 * 16) ^ ((r0 & 7) << 4));
    int swb1 = r1 * 128 + ((s1v * 16) ^ ((r1 & 7) << 4));

    int nch = (TT + 63) >> 6;
    float4 st0, st1;
    {
      int q0 = r0; if (q0 >= TT) q0 = TT - 1;
      int q1 = r1; if (q1 >= TT) q1 = TT - 1;
      st0 = *(const float4*)(zl + (size_t)q0 * C_ + s0 * 8);
      st1 = *(const float4*)(zl + (size_t)q1 * C_ + s1v * 8);
      *(float4*)(lds + swb0) = st0;
      *(float4*)(lds + swb1) = st1;
    }
    int cur = 0;

    for (int ch = 0; ch < nch; ch++) {
      __syncthreads();
      if (ch + 1 < nch) {
        int nb0 = (ch + 1) * 64 + r0; if (nb0 >= TT) nb0 = TT - 1;
        int nb1 = (ch + 1) * 64 + r1; if (nb1 >= TT) nb1 = TT - 1;
        st0 = *(const float4*)(zl + (size_t)nb0 * C_ + s0 * 8);
        st1 = *(const float4*)(zl + (size_t)nb1 * C_ + s1v * 8);
      }
      if (activew) {
        const char* base = lds + cur * 8192;
        f32x4 acc[2][4];
        #pragma unroll
        for (int tt = 0; tt < 4; tt++) {
          int br = tt * 16 + lo;
          int byt = br * 128 + ((hi * 16) ^ ((br & 7) << 4));
          bf16x8 b0 = *(const bf16x8*)(base + byt);
          bf16x8 b1 = *(const bf16x8*)(base + (byt ^ 64));
          #pragma unroll
          for (int rt = 0; rt < 2; rt++) {
            f32x4 c = {0.f, 0.f, 0.f, 0.f};
            c = __builtin_amdgcn_mfma_f32_16x16x32_bf16(a0[rt], b0, c, 0, 0, 0);
            c = __builtin_amdgcn_mfma_f32_16x16x32_bf16(a1[rt], b1, c, 0, 0, 0);
            acc[rt][tt] = c;
          }
        }
        int cb = ch << 6;
        bool maskpath = (ch == diagch) || (cb + 64 > TT);
        #pragma unroll
        for (int rt = 0; rt < 2; rt++) {
          #pragma unroll
          for (int sl = 0; sl < 4; sl++) {
            int r = rowbase + rt * 16 + hi * 4 + sl;
            if (maskpath) {
              float v[4]; float vmax = -POS_BIG;
              #pragma unroll
              for (int tt = 0; tt < 4; tt++) {
                int cg = cb + tt * 16 + lo;
                bool excl = (cg >= TT) || (cg == r);
                v[tt] = excl ? -POS_BIG : acc[rt][tt][sl];
                vmax = fmaxf(vmax, v[tt]);
              }
              if (vmax > -1e29f) {
                float mn = fmaxf(mb[rt][sl], vmax * L2E);
                float ss = s[rt][sl] * exp2f(mb[rt][sl] - mn);
                #pragma unroll
                for (int tt = 0; tt < 4; tt++) ss += exp2f(fmaf(v[tt], L2E, -mn));
                s[rt][sl] = ss; mb[rt][sl] = mn;
              }
            } else {
              float v0 = acc[rt][0][sl], v1 = acc[rt][1][sl];
              float v2 = acc[rt][2][sl], v3 = acc[rt][3][sl];
              float vmax = fmaxf(fmaxf(v0, v1), fmaxf(v2, v3));
              float mn = fmaxf(mb[rt][sl], vmax * L2E);
              float ss = s[rt][sl] * exp2f(mb[rt][sl] - mn);
              ss += exp2f(fmaf(v0, L2E, -mn)) + exp2f(fmaf(v1, L2E, -mn))
                  + exp2f(fmaf(v2, L2E, -mn)) + exp2f(fmaf(v3, L2E, -mn));
              s[rt][sl] = ss; mb[rt][sl] = mn;
            }
          }
        }
      }
      if (ch + 1 < nch) {
        char* nb = lds + (cur ^ 1) * 8192;
        *(float4*)(nb + swb0) = st0;
        *(float4*)(nb + swb1) = st1;
      }
      cur ^= 1;
    }

    float pos[2][4];
    #pragma unroll
    for (int rt = 0; rt < 2; rt++) {
      #pragma unroll
      for (int sl = 0; sl < 4; sl++) {
        pos[rt][sl] = 0.f;
        int r = rowbase + rt * 16 + hi * 4 + sl;
        if (activew && r < TT) {
          int rp = (r < T) ? r : r - T;
          float4 u = *(const float4*)(z1b + (size_t)rp * C_ + lo * 4);
          float4 v = *(const float4*)(z2b + (size_t)rp * C_ + lo * 4);
          pos[rt][sl] = u.x * v.x + u.y * v.y + u.z * v.z + u.w * v.w;
        }
      }
    }

    #pragma unroll
    for (int msk = 1; msk < 16; msk <<= 1) {
      #pragma unroll
      for (int rt = 0; rt < 2; rt++) {
        #pragma unroll
        for (int sl = 0; sl < 4; sl++) {
          float mo = __shfl_xor(mb[rt][sl], msk, 16);
          float so = __shfl_xor(s[rt][sl], msk, 16);
          float po = __shfl_xor(pos[rt][sl], msk, 16);
          float mn = fmaxf(mb[rt][sl], mo);
          s[rt][sl] = s[rt][sl] * exp2f(mb[rt][sl] - mn) + so * exp2f(mo - mn);
          mb[rt][sl] = mn;
          pos[rt][sl] += po;
        }
      }
    }

    float val = 0.f;
    if (lo == 0 && activew) {
      #pragma unroll
      for (int rt = 0; rt < 2; rt++) {
        #pragma unroll
        for (int sl = 0; sl < 4; sl++) {
          int r = rowbase + rt * 16 + hi * 4 + sl;
          if (r < TT) val += LN2 * (mb[rt][sl] + __log2f(s[rt][sl])) - pos[rt][sl];
        }
      }
    }
    #pragma unroll
    for (int off = 32; off; off >>= 1) val += __shfl_down(val, off, 64);
    float tscale = 0.5f / (11.0f * 2.0f * 16.0f * (float)T);
    if (lane == 0) atomicAdd(out, val * tscale);

  } else {
    // ================= instance (bf16 neighbor gathers for l<=9; f32 fallback l=10) =================
    float* dmin = (float*)lds;          // 64*17
    float* dLl  = dmin + 1088;
    float* dRl  = dLl + 1088;
    int*   Lp   = (int*)(dRl + 1088);
    int*   Rp   = Lp + 1088;
    int (*nbrs)[16] = (int(*)[16])(Rp + 1088);

    int bid = bid0 - NTEMP;
    int l = 0, ls = 0;
    #pragma unroll
    for (int i = 1; i < 11; i++) if (bid >= kIS[i]) { l = i; ls = kIS[i]; }
    int T = 1024 >> l, lgT = 10 - l, N = B_ * T;
    const float *z1, *z2, *t;
    if (l == 0) { z1 = z1_0; z2 = z2_0; t = t_0; }
    else {
      int i1 = 0, i2 = 0, it = 0;
      #pragma unroll
      for (int i = 1; i < 11; i++) if (l == i) { i1 = kO1[i]; i2 = kO2[i]; it = kOT[i]; }
      z1 = ws + i1; z2 = ws + i2; t = ws + it;
    }
    bool useBf = (l <= 9);
    int zo = 0;
    #pragma unroll
    for (int i = 1; i < 10; i++) if (l == i) zo = kZOff[i];
    const short* zbl = zcb + zo;     // bf16 zc layout [b][2T][64]
    float scale = 0.5f / (11.0f * (float)N);
    int rbase = (bid - ls) * 64;

    if (T == 1) {
      for (int i2x = tid; i2x < 64 * 16; i2x += 256)
        nbrs[i2x >> 4][i2x & 15] = i2x & 15;
    } else {
      // ---- A0: 64 rows x 15 seqs parallel branchless searches ----
      for (int i2x = tid; i2x < 64 * 16; i2x += 256) {
        int r = i2x >> 4, s = i2x & 15;
        int n = rbase + r;
        if (s < 15 && n < N) {
          int bq = n >> lgT;
          float q = t[n];
          int bs = s + (s >= bq ? 1 : 0);
          const float* tb = t + (bs << lgT);
          int li = 0;
          for (int k = T >> 1; k; k >>= 1) li += (tb[li + k - 1] < q) ? k : 0;
          li += (tb[li] < q) ? 1 : 0;
          float dl = (li >= 1) ? (q - tb[li - 1]) : POS_BIG;
          float dr = (li < T)  ? (tb[li] - q)     : POS_BIG;
          int o = r * 17 + s;
          Lp[o] = li - 1; Rp[o] = li;
          dLl[o] = dl; dRl[o] = dr; dmin[o] = fminf(dl, dr);
        }
      }
    }
    __syncthreads();

    // ---- A1: per-row 16-step merge (16 lanes of each wave) ----
    if (T > 1 && lane < 16) {
      int r = wv * 16 + lane;
      int n = rbase + r;
      if (n < N) {
        int bq = n >> lgT;
        float q = t[n];
        #pragma unroll 1
        for (int j = 0; j < 16; j++) {
          float best = dmin[r * 17]; int sb = 0;
          #pragma unroll
          for (int s = 1; s < 15; s++) {
            float c = dmin[r * 17 + s];
            bool lt = c < best; best = lt ? c : best; sb = lt ? s : sb;
          }
          int o = r * 17 + sb;
          int bs = sb + (sb >= bq ? 1 : 0);
          float dl = dLl[o], dr = dRl[o];
          if (dl <= dr) {
            int p = Lp[o];
            nbrs[r][j] = bs * T + p;
            int pn = p - 1; Lp[o] = pn;
            float nd = (pn >= 0) ? (q - t[bs * T + pn]) : POS_BIG;
            dLl[o] = nd; dmin[o] = fminf(nd, dr);
          } else {
            int p = Rp[o];
            nbrs[r][j] = bs * T + p;
            int pn = p + 1; Rp[o] = pn;
            float nd = (pn < T) ? (t[bs * T + pn] - q) : POS_BIG;
            dRl[o] = nd; dmin[o] = fminf(dl, nd);
          }
        }
      } else {
        #pragma unroll
        for (int j = 0; j < 16; j++) nbrs[r][j] = 0;
      }
    }
    __syncthreads();

    // ---- B: wave-cooperative dots (16 lanes per row; bf16 neighbor rows when available) ----
    int g = lane >> 4, sl = lane & 15;
    float loss = 0.f;
    #pragma unroll 1
    for (int rc = 0; rc < 4; rc++) {
      int r = wv * 16 + rc * 4 + g;
      int n = rbase + r;
      bool act = n < N;
      int ns = act ? n : rbase;
      float4 za = *(const float4*)(z1 + (size_t)ns * C_ + sl * 4);
      float4 zp = *(const float4*)(z2 + (size_t)ns * C_ + sl * 4);
      float pos = za.x * zp.x + za.y * zp.y + za.z * zp.z + za.w * zp.w;
      float a11[16], a12[16];
      if (useBf) {
        #pragma unroll
        for (int j = 0; j < 16; j++) {
          int nb = nbrs[r][j];
          int bb = nb >> lgT;
          int ii = nb - (bb << lgT);
          const short* p1 = zbl + ((size_t)bb * 2 * T + ii) * C_ + sl * 4;
          ushort4 u1 = *(const ushort4*)p1;
          ushort4 u2 = *(const ushort4*)(p1 + (size_t)T * C_);
          a11[j] = za.x * b2f(u1.x) + za.y * b2f(u1.y) + za.z * b2f(u1.z) + za.w * b2f(u1.w);
          a12[j] = za.x * b2f(u2.x) + za.y * b2f(u2.y) + za.z * b2f(u2.z) + za.w * b2f(u2.w);
        }
      } else {
        #pragma unroll
        for (int j = 0; j < 16; j++) {
          int nb = nbrs[r][j];
          float4 uu = *(const float4*)(z1 + (size_t)nb * C_ + sl * 4);
          float4 vv = *(const float4*)(z2 + (size_t)nb * C_ + sl * 4);
          a11[j] = za.x * uu.x + za.y * uu.y + za.z * uu.z + za.w * uu.w;
          a12[j] = za.x * vv.x + za.y * vv.y + za.z * vv.z + za.w * vv.w;
        }
      }
      #pragma unroll
      for (int msk = 1; msk < 16; msk <<= 1) {
        pos += __shfl_xor(pos, msk, 16);
        #pragma unroll
        for (int j = 0; j < 16; j++) {
          a11[j] += __shfl_xor(a11[j], msk, 16);
          a12[j] += __shfl_xor(a12[j], msk, 16);
        }
      }
      if (sl == 0 && act) {
        float m = pos;
        #pragma unroll
        for (int j = 0; j < 16; j++) m = fmaxf(m, fmaxf(a11[j], a12[j]));
        float se = __expf(pos - m);
        #pragma unroll
        for (int j = 0; j < 16; j++) se += __expf(a11[j] - m) + __expf(a12[j] - m);
        loss += (m + __logf(se)) - pos;
      }
    }
    #pragma unroll
    for (int off = 32; off; off >>= 1) loss += __shfl_down(loss, off, 64);
    if (lane == 0) atomicAdd(out, loss * scale);
  }
}

// ---------------- host side ----------------
extern "C" void kernel_launch(void* const* d_in, const int* in_sizes, int n_in,
                              void* d_out, int out_size, void* d_ws, size_t ws_size,
                              hipStream_t stream)
{
  (void)in_sizes; (void)n_in; (void)out_size; (void)ws_size;
  const float* z1_0 = (const float*)d_in[0];
  const float* z2_0 = (const float*)d_in[1];
  const float* t_0  = (const float*)d_in[2];
  float* out = (float*)d_out;
  float* ws  = (float*)d_ws;

  short* zcb = (short*)(ws + 2111472);   // bf16 zc pyramid after f32 pyramid

  hipMemsetAsync(d_out, 0, sizeof(float), stream);
  hipLaunchKernelGGL(pyramid1_kernel, dim3(4542), dim3(256), 0, stream,
                     z1_0, z2_0, t_0, ws, zcb);
  hipLaunchKernelGGL(pyramid2_kernel, dim3(126), dim3(256), 0, stream, ws, zcb);
  hipLaunchKernelGGL(loss_fused, dim3(NTEMP + NINST), dim3(256), 0, stream,
                     z1_0, z2_0, t_0, ws, zcb, out);
}

// Round 17
// 133.913 us; speedup vs baseline: 1.2514x; 1.0618x over previous
//
#include <hip/hip_runtime.h>
#include <hip/hip_bf16.h>
#include <math.h>

#define B_ 16
#define C_ 64
#define POS_BIG (1e30f)
#define L2E 1.44269504088896340736f
#define LN2 0.69314718055994530942f

typedef __attribute__((ext_vector_type(8))) short bf16x8;
typedef __attribute__((ext_vector_type(4))) float f32x4;

__device__ __forceinline__ short f2bf(float x) {
  __hip_bfloat16 h = __float2bfloat16(x);
  return *reinterpret_cast<short*>(&h);
}

// ---- compile-time tables (fixed problem B=16, T=1024, C=64) ----
// temporal: 576 blocks (128 rows each); starts per level l=0..9
__device__ constexpr int kTS[10]   = {0, 256, 384, 448, 480, 496, 512, 528, 544, 560};
__device__ constexpr int kZOff[10] = {0, 2097152, 3145728, 3670016, 3932160, 4063232,
                                      4128768, 4161536, 4177920, 4186112};               // shorts
// instance: 513 blocks; starts per level l=0..10
__device__ constexpr int kIS[11] = {0, 256, 384, 448, 480, 496, 504, 508, 510, 511, 512};
// f32 pyramid offsets in ws (floats), l=1..10
__device__ constexpr int kO1[11] = {0, 0, 1056768, 1585152, 1849344, 1981440, 2047488,
                                    2080512, 2097024, 2105280, 2109408};
__device__ constexpr int kO2[11] = {0, 524288, 1318912, 1716224, 1914880, 2014208, 2063872,
                                    2088704, 2101120, 2107328, 2110432};
__device__ constexpr int kOT[11] = {0, 1048576, 1581056, 1847296, 1980416, 2046976, 2080256,
                                    2096896, 2105216, 2109376, 2111456};

#define NTEMP 576
#define NINST 513

// ---------------- pyramid stage 1: L0 bf16 convert + levels 1..5 direct from L0 ----------------
__global__ __launch_bounds__(256) void pyramid1_kernel(
    const float* __restrict__ z1, const float* __restrict__ z2, const float* __restrict__ t,
    float* __restrict__ ws, short* __restrict__ zcb)
{
  int idx = blockIdx.x * 256 + threadIdx.x;
  if (idx < 131072) {
    int n = idx * 8;
    int b = n >> 16;
    float4 u1 = *(const float4*)(z1 + n), v1 = *(const float4*)(z1 + n + 4);
    float4 u2 = *(const float4*)(z2 + n), v2 = *(const float4*)(z2 + n + 4);
    bf16x8 f1, f2;
    f1[0]=f2bf(u1.x); f1[1]=f2bf(u1.y); f1[2]=f2bf(u1.z); f1[3]=f2bf(u1.w);
    f1[4]=f2bf(v1.x); f1[5]=f2bf(v1.y); f1[6]=f2bf(v1.z); f1[7]=f2bf(v1.w);
    f2[0]=f2bf(u2.x); f2[1]=f2bf(u2.y); f2[2]=f2bf(u2.z); f2[3]=f2bf(u2.w);
    f2[4]=f2bf(v2.x); f2[5]=f2bf(v2.y); f2[6]=f2bf(v2.z); f2[7]=f2bf(v2.w);
    *(bf16x8*)(zcb + (size_t)n + (size_t)b * 65536) = f1;
    *(bf16x8*)(zcb + (size_t)n + (size_t)(b + 1) * 65536) = f2;
  } else if (idx < 1146880) {
    int li = idx - 131072;
    int l = 1, st = 0;
    if (li >= 524288) { l = 2; st = 524288; }
    if (li >= 786432) { l = 3; st = 786432; }
    if (li >= 917504) { l = 4; st = 917504; }
    if (li >= 983040) { l = 5; st = 983040; }
    int k = li - st;
    int c = k & 63, bi = k >> 6;
    int Tl = 1024 >> l;
    int i = bi & (Tl - 1), b = bi >> (10 - l);
    int w = 1 << l;
    const float* p1 = z1 + ((((size_t)b << 10) + ((size_t)i << l)) << 6) + c;
    const float* p2 = z2 + ((((size_t)b << 10) + ((size_t)i << l)) << 6) + c;
    float m1 = p1[0], m2 = p2[0];
    #pragma unroll 4
    for (int j = 1; j < w; j++) { m1 = fmaxf(m1, p1[(size_t)j << 6]); m2 = fmaxf(m2, p2[(size_t)j << 6]); }
    int o1 = 0, o2 = 0, zo = 0;
    #pragma unroll
    for (int q = 1; q <= 5; q++) if (l == q) { o1 = kO1[q]; o2 = kO2[q]; zo = kZOff[q]; }
    ws[o1 + k] = m1; ws[o2 + k] = m2;
    int zi = zo + ((b * 2 * Tl + i) << 6) + c;
    zcb[zi] = f2bf(m1);
    zcb[zi + (Tl << 6)] = f2bf(m2);
  } else if (idx < 1162752) {
    int kt = idx - 1146880;
    int l = 1, st = 0;
    if (kt >= 8192)  { l = 2; st = 8192; }
    if (kt >= 12288) { l = 3; st = 12288; }
    if (kt >= 14336) { l = 4; st = 14336; }
    if (kt >= 15360) { l = 5; st = 15360; }
    int k = kt - st;
    int Tl = 1024 >> l;
    int i = k & (Tl - 1), b = k >> (10 - l);
    int w = 1 << l;
    const float* pt = t + ((size_t)b << 10) + ((size_t)i << l);
    float sum = 0.f;
    #pragma unroll 4
    for (int j = 0; j < w; j++) sum += pt[j];
    int ot = 0;
    #pragma unroll
    for (int q = 1; q <= 5; q++) if (l == q) ot = kOT[q];
    ws[ot + k] = sum / (float)w;
  }
}

// ---------------- pyramid stage 2: levels 6..10 from level 5 ----------------
__global__ __launch_bounds__(256) void pyramid2_kernel(
    float* __restrict__ ws, short* __restrict__ zcb)
{
  int idx = blockIdx.x * 256 + threadIdx.x;
  const float* z15 = ws + kO1[5];
  const float* z25 = ws + kO2[5];
  const float* t5  = ws + kOT[5];
  if (idx < 31744) {
    int l = 6, st = 0;
    if (idx >= 16384) { l = 7;  st = 16384; }
    if (idx >= 24576) { l = 8;  st = 24576; }
    if (idx >= 28672) { l = 9;  st = 28672; }
    if (idx >= 30720) { l = 10; st = 30720; }
    int k = idx - st;
    int c = k & 63, bi = k >> 6;
    int Tl = 1024 >> l;
    int i = bi & (Tl - 1), b = bi >> (10 - l);
    int w = 1 << (l - 5);
    const float* p1 = z15 + ((((size_t)b << 5) + ((size_t)i << (l - 5))) << 6) + c;
    const float* p2 = z25 + ((((size_t)b << 5) + ((size_t)i << (l - 5))) << 6) + c;
    float m1 = p1[0], m2 = p2[0];
    #pragma unroll 4
    for (int j = 1; j < w; j++) { m1 = fmaxf(m1, p1[(size_t)j << 6]); m2 = fmaxf(m2, p2[(size_t)j << 6]); }
    int o1 = 0, o2 = 0, zo = 0;
    #pragma unroll
    for (int q = 6; q <= 10; q++) if (l == q) { o1 = kO1[q]; o2 = kO2[q]; zo = (q <= 9) ? kZOff[q] : -1; }
    ws[o1 + k] = m1; ws[o2 + k] = m2;
    if (l <= 9) {
      int zi = zo + ((b * 2 * Tl + i) << 6) + c;
      zcb[zi] = f2bf(m1);
      zcb[zi + (Tl << 6)] = f2bf(m2);
    }
  } else if (idx < 32240) {
    int kt = idx - 31744;
    int l = 6, st = 0;
    if (kt >= 256) { l = 7;  st = 256; }
    if (kt >= 384) { l = 8;  st = 384; }
    if (kt >= 448) { l = 9;  st = 448; }
    if (kt >= 480) { l = 10; st = 480; }
    int k = kt - st;
    int Tl = 1024 >> l;
    int i = k & (Tl - 1), b = k >> (10 - l);
    int w = 1 << (l - 5);
    const float* pt = t5 + ((size_t)b << 5) + ((size_t)i << (l - 5));
    float sum = 0.f;
    #pragma unroll
    for (int j = 0; j < w; j++) sum += pt[j];
    int ot = 0;
    #pragma unroll
    for (int q = 6; q <= 10; q++) if (l == q) ot = kOT[q];
    ws[ot + k] = sum / (float)w;
  }
}

// ---------------- fused loss: temporal (blocks 0..575) then instance (blocks 576..1088) ----------------
__global__ __launch_bounds__(256) void loss_fused(
    const float* __restrict__ z1_0, const float* __restrict__ z2_0, const float* __restrict__ t_0,
    const float* __restrict__ ws, const short* __restrict__ zcb, float* __restrict__ out)
{
  __shared__ __align__(16) char lds[25856];   // union: temporal 2x8KB dbuf | instance state
  int bid0 = blockIdx.x;
  int tid = threadIdx.x;
  int wv = tid >> 6, lane = tid & 63, lo = lane & 15, hi = lane >> 4;

  if (bid0 < NTEMP) {
    // ================= temporal (128 rows, 4 waves, TCH=64, 1 barrier/chunk) =================
    int bid = (bid0 & 7) * 72 + (bid0 >> 3);   // bijective XCD swizzle (576 = 8*72)

    int l = 0, ls = 0;
    #pragma unroll
    for (int i = 1; i < 10; i++) if (bid >= kTS[i]) { l = i; ls = kTS[i]; }
    int T = 1024 >> l, TT = 2 * T;
    int lb = bid - ls;
    int lg = (4 - l) > 0 ? (4 - l) : 0;        // log2(128-row blocks per batch)
    int b = lb >> lg, rblk = lb & ((1 << lg) - 1);

    int zoff = 0, fo1 = 0, fo2 = 0;
    #pragma unroll
    for (int i = 1; i < 10; i++) if (l == i) { zoff = kZOff[i]; fo1 = kO1[i]; fo2 = kO2[i]; }
    const short* zl = zcb + zoff + (size_t)b * TT * C_;
    const float* z1b = ((l == 0) ? z1_0 : ws + fo1) + (size_t)b * T * C_;
    const float* z2b = ((l == 0) ? z2_0 : ws + fo2) + (size_t)b * T * C_;

    int rowbase = rblk * 128 + wv * 32;
    bool activew = rowbase < TT;
    int diagch = rowbase >> 6;

    bf16x8 a0[2], a1[2];
    #pragma unroll
    for (int rt = 0; rt < 2; rt++) {
      int ar = rowbase + rt * 16 + lo; if (ar >= TT) ar = TT - 1;
      const short* pa = zl + (size_t)ar * C_;
      a0[rt] = *(const bf16x8*)(pa + hi * 8);
      a1[rt] = *(const bf16x8*)(pa + 32 + hi * 8);
    }

    float mb[2][4], s[2][4];                   // online LSE state, log2 units
    #pragma unroll
    for (int rt = 0; rt < 2; rt++)
      #pragma unroll
      for (int sl = 0; sl < 4; sl++) { mb[rt][sl] = -POS_BIG; s[rt][sl] = 0.f; }

    int r0 = tid >> 3, s0 = tid & 7;
    int r1 = r0 + 32, s1v = s0;
    int swb0 = r0 * 128 + ((s0 * 16) ^ ((r0 & 7) << 4));
    int swb1 = r1 * 128 + ((s1v * 16) ^ ((r1 & 7) << 4));

    int nch = (TT + 63) >> 6;
    float4 st0, st1;
    {
      int q0 = r0; if (q0 >= TT) q0 = TT - 1;
      int q1 = r1; if (q1 >= TT) q1 = TT - 1;
      st0 = *(const float4*)(zl + (size_t)q0 * C_ + s0 * 8);
      st1 = *(const float4*)(zl + (size_t)q1 * C_ + s1v * 8);
      *(float4*)(lds + swb0) = st0;
      *(float4*)(lds + swb1) = st1;
    }
    int cur = 0;

    for (int ch = 0; ch < nch; ch++) {
      __syncthreads();
      if (ch + 1 < nch) {
        int nb0 = (ch + 1) * 64 + r0; if (nb0 >= TT) nb0 = TT - 1;
        int nb1 = (ch + 1) * 64 + r1; if (nb1 >= TT) nb1 = TT - 1;
        st0 = *(const float4*)(zl + (size_t)nb0 * C_ + s0 * 8);
        st1 = *(const float4*)(zl + (size_t)nb1 * C_ + s1v * 8);
      }
      if (activew) {
        const char* base = lds + cur * 8192;
        f32x4 acc[2][4];
        #pragma unroll
        for (int tt = 0; tt < 4; tt++) {
          int br = tt * 16 + lo;
          int byt = br * 128 + ((hi * 16) ^ ((br & 7) << 4));
          bf16x8 b0 = *(const bf16x8*)(base + byt);
          bf16x8 b1 = *(const bf16x8*)(base + (byt ^ 64));
          #pragma unroll
          for (int rt = 0; rt < 2; rt++) {
            f32x4 c = {0.f, 0.f, 0.f, 0.f};
            c = __builtin_amdgcn_mfma_f32_16x16x32_bf16(a0[rt], b0, c, 0, 0, 0);
            c = __builtin_amdgcn_mfma_f32_16x16x32_bf16(a1[rt], b1, c, 0, 0, 0);
            acc[rt][tt] = c;
          }
        }
        int cb = ch << 6;
        bool maskpath = (ch == diagch) || (cb + 64 > TT);
        #pragma unroll
        for (int rt = 0; rt < 2; rt++) {
          #pragma unroll
          for (int sl = 0; sl < 4; sl++) {
            int r = rowbase + rt * 16 + hi * 4 + sl;
            if (maskpath) {
              float v[4]; float vmax = -POS_BIG;
              #pragma unroll
              for (int tt = 0; tt < 4; tt++) {
                int cg = cb + tt * 16 + lo;
                bool excl = (cg >= TT) || (cg == r);
                v[tt] = excl ? -POS_BIG : acc[rt][tt][sl];
                vmax = fmaxf(vmax, v[tt]);
              }
              if (vmax > -1e29f) {
                float mn = fmaxf(mb[rt][sl], vmax * L2E);
                float ss = s[rt][sl] * exp2f(mb[rt][sl] - mn);
                #pragma unroll
                for (int tt = 0; tt < 4; tt++) ss += exp2f(fmaf(v[tt], L2E, -mn));
                s[rt][sl] = ss; mb[rt][sl] = mn;
              }
            } else {
              float v0 = acc[rt][0][sl], v1 = acc[rt][1][sl];
              float v2 = acc[rt][2][sl], v3 = acc[rt][3][sl];
              float vmax = fmaxf(fmaxf(v0, v1), fmaxf(v2, v3));
              float mn = fmaxf(mb[rt][sl], vmax * L2E);
              float ss = s[rt][sl] * exp2f(mb[rt][sl] - mn);
              ss += exp2f(fmaf(v0, L2E, -mn)) + exp2f(fmaf(v1, L2E, -mn))
                  + exp2f(fmaf(v2, L2E, -mn)) + exp2f(fmaf(v3, L2E, -mn));
              s[rt][sl] = ss; mb[rt][sl] = mn;
            }
          }
        }
      }
      if (ch + 1 < nch) {
        char* nb = lds + (cur ^ 1) * 8192;
        *(float4*)(nb + swb0) = st0;
        *(float4*)(nb + swb1) = st1;
      }
      cur ^= 1;
    }

    float pos[2][4];
    #pragma unroll
    for (int rt = 0; rt < 2; rt++) {
      #pragma unroll
      for (int sl = 0; sl < 4; sl++) {
        pos[rt][sl] = 0.f;
        int r = rowbase + rt * 16 + hi * 4 + sl;
        if (activew && r < TT) {
          int rp = (r < T) ? r : r - T;
          float4 u = *(const float4*)(z1b + (size_t)rp * C_ + lo * 4);
          float4 v = *(const float4*)(z2b + (size_t)rp * C_ + lo * 4);
          pos[rt][sl] = u.x * v.x + u.y * v.y + u.z * v.z + u.w * v.w;
        }
      }
    }

    #pragma unroll
    for (int msk = 1; msk < 16; msk <<= 1) {
      #pragma unroll
      for (int rt = 0; rt < 2; rt++) {
        #pragma unroll
        for (int sl = 0; sl < 4; sl++) {
          float mo = __shfl_xor(mb[rt][sl], msk, 16);
          float so = __shfl_xor(s[rt][sl], msk, 16);
          float po = __shfl_xor(pos[rt][sl], msk, 16);
          float mn = fmaxf(mb[rt][sl], mo);
          s[rt][sl] = s[rt][sl] * exp2f(mb[rt][sl] - mn) + so * exp2f(mo - mn);
          mb[rt][sl] = mn;
          pos[rt][sl] += po;
        }
      }
    }

    float val = 0.f;
    if (lo == 0 && activew) {
      #pragma unroll
      for (int rt = 0; rt < 2; rt++) {
        #pragma unroll
        for (int sl = 0; sl < 4; sl++) {
          int r = rowbase + rt * 16 + hi * 4 + sl;
          if (r < TT) val += LN2 * (mb[rt][sl] + __log2f(s[rt][sl])) - pos[rt][sl];
        }
      }
    }
    #pragma unroll
    for (int off = 32; off; off >>= 1) val += __shfl_down(val, off, 64);
    float tscale = 0.5f / (11.0f * 2.0f * 16.0f * (float)T);
    if (lane == 0) atomicAdd(out, val * tscale);

  } else {
    // ================= instance (16-lane coalesced phase B) =================
    float* dmin = (float*)lds;          // 64*17
    float* dLl  = dmin + 1088;
    float* dRl  = dLl + 1088;
    int*   Lp   = (int*)(dRl + 1088);
    int*   Rp   = Lp + 1088;
    int (*nbrs)[16] = (int(*)[16])(Rp + 1088);

    int bid = bid0 - NTEMP;
    int l = 0, ls = 0;
    #pragma unroll
    for (int i = 1; i < 11; i++) if (bid >= kIS[i]) { l = i; ls = kIS[i]; }
    int T = 1024 >> l, lgT = 10 - l, N = B_ * T;
    const float *z1, *z2, *t;
    if (l == 0) { z1 = z1_0; z2 = z2_0; t = t_0; }
    else {
      int i1 = 0, i2 = 0, it = 0;
      #pragma unroll
      for (int i = 1; i < 11; i++) if (l == i) { i1 = kO1[i]; i2 = kO2[i]; it = kOT[i]; }
      z1 = ws + i1; z2 = ws + i2; t = ws + it;
    }
    float scale = 0.5f / (11.0f * (float)N);
    int rbase = (bid - ls) * 64;

    if (T == 1) {
      for (int i2x = tid; i2x < 64 * 16; i2x += 256)
        nbrs[i2x >> 4][i2x & 15] = i2x & 15;
    } else {
      // ---- A0: 64 rows x 15 seqs parallel branchless searches ----
      for (int i2x = tid; i2x < 64 * 16; i2x += 256) {
        int r = i2x >> 4, s = i2x & 15;
        int n = rbase + r;
        if (s < 15 && n < N) {
          int bq = n >> lgT;
          float q = t[n];
          int bs = s + (s >= bq ? 1 : 0);
          const float* tb = t + (bs << lgT);
          int li = 0;
          for (int k = T >> 1; k; k >>= 1) li += (tb[li + k - 1] < q) ? k : 0;
          li += (tb[li] < q) ? 1 : 0;
          float dl = (li >= 1) ? (q - tb[li - 1]) : POS_BIG;
          float dr = (li < T)  ? (tb[li] - q)     : POS_BIG;
          int o = r * 17 + s;
          Lp[o] = li - 1; Rp[o] = li;
          dLl[o] = dl; dRl[o] = dr; dmin[o] = fminf(dl, dr);
        }
      }
    }
    __syncthreads();

    // ---- A1: per-row 16-step merge (16 lanes of each wave) ----
    if (T > 1 && lane < 16) {
      int r = wv * 16 + lane;
      int n = rbase + r;
      if (n < N) {
        int bq = n >> lgT;
        float q = t[n];
        #pragma unroll 1
        for (int j = 0; j < 16; j++) {
          float best = dmin[r * 17]; int sb = 0;
          #pragma unroll
          for (int s = 1; s < 15; s++) {
            float c = dmin[r * 17 + s];
            bool lt = c < best; best = lt ? c : best; sb = lt ? s : sb;
          }
          int o = r * 17 + sb;
          int bs = sb + (sb >= bq ? 1 : 0);
          float dl = dLl[o], dr = dRl[o];
          if (dl <= dr) {
            int p = Lp[o];
            nbrs[r][j] = bs * T + p;
            int pn = p - 1; Lp[o] = pn;
            float nd = (pn >= 0) ? (q - t[bs * T + pn]) : POS_BIG;
            dLl[o] = nd; dmin[o] = fminf(nd, dr);
          } else {
            int p = Rp[o];
            nbrs[r][j] = bs * T + p;
            int pn = p + 1; Rp[o] = pn;
            float nd = (pn < T) ? (t[bs * T + pn] - q) : POS_BIG;
            dRl[o] = nd; dmin[o] = fminf(dl, nd);
          }
        }
      } else {
        #pragma unroll
        for (int j = 0; j < 16; j++) nbrs[r][j] = 0;
      }
    }
    __syncthreads();

    // ---- B: wave-cooperative dots (16 lanes per row, coalesced 256B rows) ----
    int g = lane >> 4, sl = lane & 15;
    float loss = 0.f;
    #pragma unroll 1
    for (int rc = 0; rc < 4; rc++) {
      int r = wv * 16 + rc * 4 + g;
      int n = rbase + r;
      bool act = n < N;
      int ns = act ? n : rbase;
      float4 za = *(const float4*)(z1 + (size_t)ns * C_ + sl * 4);
      float4 zp = *(const float4*)(z2 + (size_t)ns * C_ + sl * 4);
      float pos = za.x * zp.x + za.y * zp.y + za.z * zp.z + za.w * zp.w;
      float a11[16], a12[16];
      #pragma unroll
      for (int j = 0; j < 16; j++) {
        int nb = nbrs[r][j];
        float4 uu = *(const float4*)(z1 + (size_t)nb * C_ + sl * 4);
        float4 vv = *(const float4*)(z2 + (size_t)nb * C_ + sl * 4);
        a11[j] = za.x * uu.x + za.y * uu.y + za.z * uu.z + za.w * uu.w;
        a12[j] = za.x * vv.x + za.y * vv.y + za.z * vv.z + za.w * vv.w;
      }
      #pragma unroll
      for (int msk = 1; msk < 16; msk <<= 1) {
        pos += __shfl_xor(pos, msk, 16);
        #pragma unroll
        for (int j = 0; j < 16; j++) {
          a11[j] += __shfl_xor(a11[j], msk, 16);
          a12[j] += __shfl_xor(a12[j], msk, 16);
        }
      }
      if (sl == 0 && act) {
        float m = pos;
        #pragma unroll
        for (int j = 0; j < 16; j++) m = fmaxf(m, fmaxf(a11[j], a12[j]));
        float se = __expf(pos - m);
        #pragma unroll
        for (int j = 0; j < 16; j++) se += __expf(a11[j] - m) + __expf(a12[j] - m);
        loss += (m + __logf(se)) - pos;
      }
    }
    #pragma unroll
    for (int off = 32; off; off >>= 1) loss += __shfl_down(loss, off, 64);
    if (lane == 0) atomicAdd(out, loss * scale);
  }
}

// ---------------- host side ----------------
extern "C" void kernel_launch(void* const* d_in, const int* in_sizes, int n_in,
                              void* d_out, int out_size, void* d_ws, size_t ws_size,
                              hipStream_t stream)
{
  (void)in_sizes; (void)n_in; (void)out_size; (void)ws_size;
  const float* z1_0 = (const float*)d_in[0];
  const float* z2_0 = (const float*)d_in[1];
  const float* t_0  = (const float*)d_in[2];
  float* out = (float*)d_out;
  float* ws  = (float*)d_ws;

  short* zcb = (short*)(ws + 2111472);   // bf16 zc pyramid after f32 pyramid

  hipMemsetAsync(d_out, 0, sizeof(float), stream);
  hipLaunchKernelGGL(pyramid1_kernel, dim3(4542), dim3(256), 0, stream,
                     z1_0, z2_0, t_0, ws, zcb);
  hipLaunchKernelGGL(pyramid2_kernel, dim3(126), dim3(256), 0, stream, ws, zcb);
  hipLaunchKernelGGL(loss_fused, dim3(NTEMP + NINST), dim3(256), 0, stream,
                     z1_0, z2_0, t_0, ws, zcb, out);
}